// Round 21
// baseline (55.045 us; speedup 1.0000x reference)
//
#include <hip/hip_runtime.h>
#include <math.h>

#define B 8
#define C 64
#define CI 32
#define N 2304        // 48*48
#define NT 36         // tiles of 64
#define NTILES (B*NT) // 288
#define NTOT (B*N)    // 18432
#define BN_EPS 1e-5

// ---- workspace layout (float offsets) ----
#define OFF_GX   0                      // [B][N][CI] g_x
#define OFF_A    (OFF_GX + B*N*CI)      // [B][N]
#define OFF_C    (OFF_A + B*N)          // [B][N]
#define OFF_SC   (OFF_C + B*N)          // [B][N] sorted desc
#define OFF_SIDX (OFF_SC + B*N)         // [B][N] int
#define OFF_KN   (OFF_SIDX + B*N)       // [B][N] int: k(n)=#{j: c_j > -a_n}
#define OFF_PLOC (OFF_KN + B*N)         // [B][N][64] excl. in-tile prefix (g | c*g)
#define OFF_TOT  (OFF_PLOC + B*N*64)    // [B][NT][64] tile totals
#define OFF_PART (OFF_TOT + B*NT*64)    // [NTILES][128] f32 per-tile partials
#define OFF_WY   (OFF_PART + NTILES*128) // [B][C][N] wy (pre-BN)

// ------------------------------------------------------------------
// K1: 288 blocks x 1024 thr (16 waves). Thread (p, wv): position, 2 channels.
// gw staged in LDS (r17 A/B); TLP split validated r19/r20.
__global__ __launch_bounds__(1024) void k_proj(
    const float* __restrict__ x,
    const float* __restrict__ g_w, const float* __restrict__ g_b,
    const float* __restrict__ th_w, const float* __restrict__ th_b,
    const float* __restrict__ ph_w, const float* __restrict__ ph_b,
    const float* __restrict__ cp_wt, const float* __restrict__ cp_wp,
    float* __restrict__ ws)
{
    __shared__ float gw[CI*C];      // [i][c] (c contiguous)
    __shared__ float tw[C], pw[C];
    __shared__ float gb[CI];
    __shared__ float tpb[2];
    const int tid = threadIdx.x;
    const int blk = blockIdx.x;     // b*NT + t
    const int b  = blk / NT;
    const int n0 = (blk % NT) * 64;

    for (int i = tid; i < CI*C; i += 1024) gw[i] = g_w[i];
    if (tid < C) {
        float s = 0.f;
        for (int i = 0; i < CI; i++) s += cp_wt[i] * th_w[i*C + tid];
        tw[tid] = s;
    } else if (tid < 2*C) {
        int c = tid - C; float s = 0.f;
        for (int i = 0; i < CI; i++) s += cp_wp[i] * ph_w[i*C + c];
        pw[c] = s;
    } else if (tid < 2*C + CI) {
        gb[tid - 2*C] = g_b[tid - 2*C];
    } else if (tid == 2*C + CI) {
        float s = 0.f; for (int i = 0; i < CI; i++) s += cp_wt[i]*th_b[i]; tpb[0] = s;
    } else if (tid == 2*C + CI + 1) {
        float s = 0.f; for (int i = 0; i < CI; i++) s += cp_wp[i]*ph_b[i]; tpb[1] = s;
    }
    __syncthreads();

    const int p = tid & 63, wv = tid >> 6;     // wv 0..15
    const int n = n0 + p;
    const int ch0 = wv*2;                      // 16 waves x 2 channels = CI
    const float* xb = x + (size_t)b*C*N + n;
    float acc0 = 0.f, acc1 = 0.f;
    float aa = 0.f, cc = 0.f;
    #pragma unroll 4
    for (int c4 = 0; c4 < C; c4 += 4) {
        float xv0 = xb[(size_t)(c4+0)*N];          // coalesced over p
        float xv1 = xb[(size_t)(c4+1)*N];
        float xv2 = xb[(size_t)(c4+2)*N];
        float xv3 = xb[(size_t)(c4+3)*N];
        if (wv == 0) {                              // wave-uniform branch
            float4 t4 = *(const float4*)(tw + c4);
            aa += t4.x*xv0 + t4.y*xv1 + t4.z*xv2 + t4.w*xv3;
        } else if (wv == 1) {
            float4 p4 = *(const float4*)(pw + c4);
            cc += p4.x*xv0 + p4.y*xv1 + p4.z*xv2 + p4.w*xv3;
        }
        float4 g0 = *(const float4*)(gw + (ch0+0)*C + c4);   // b128 broadcast
        float4 g1 = *(const float4*)(gw + (ch0+1)*C + c4);
        acc0 += g0.x*xv0 + g0.y*xv1 + g0.z*xv2 + g0.w*xv3;
        acc1 += g1.x*xv0 + g1.y*xv1 + g1.z*xv2 + g1.w*xv3;
    }
    acc0 += gb[ch0]; acc1 += gb[ch0 + 1];
    float* gxp = ws + OFF_GX + ((size_t)(b*N + n))*CI + ch0;
    *(float2*)(gxp) = make_float2(acc0, acc1);
    if (wv == 0) ws[OFF_A + b*N + n] = aa + tpb[0];
    else if (wv == 1) ws[OFF_C + b*N + n] = cc + tpb[1];
}

// ------------------------------------------------------------------
// K2: rank-by-counting with u64 keys + k-count. 1024 thr / 16 waves, each
// scans N/16 of the keys (TLP lever validated r19/r20).
__global__ __launch_bounds__(1024) void k_rank(float* __restrict__ ws)
{
    __shared__ __align__(16) unsigned long long keys[N];   // 18 KB
    __shared__ int partial[1024];
    __shared__ int partial2[1024];
    __shared__ float av[64];
    const int tid = threadIdx.x;
    const int blk = blockIdx.x;      // b*NT + mtile
    const int b  = blk / NT;
    const int m0 = (blk % NT) * 64;
    const float* cb = ws + OFF_C + (size_t)b*N;
    for (int i = tid; i < N; i += 1024) {
        unsigned int u = __float_as_uint(cb[i]);
        unsigned int k32 = (u & 0x80000000u) ? ~u : (u | 0x80000000u);
        keys[i] = ((unsigned long long)k32 << 12) | (unsigned long long)(4095 - i);
    }
    if (tid < 64) av[tid] = ws[OFF_A + b*N + m0 + tid];
    __syncthreads();
    const int p = tid & 63;
    const int wv = tid >> 6;                   // wave id = j-sixteenth (0..15)
    const unsigned long long my = keys[m0 + p];
    unsigned int ua  = __float_as_uint(-av[p]);
    unsigned int t32 = (ua & 0x80000000u) ? ~ua : (ua | 0x80000000u);
    const unsigned long long thr = ((unsigned long long)t32 << 12) | 4095ull;
    const ulonglong2* kp = (const ulonglong2*)keys;
    int c0=0,c1=0,c2=0,c3=0, d0=0,d1=0,d2=0,d3=0;
    const int base = wv * (N/32);              // N/2 ulonglong2 / 16 waves = 72
    #pragma unroll 4
    for (int t2 = 0; t2 < N/32; t2 += 2) {     // 2 x ulonglong2 per iter
        ulonglong2 ka = kp[base + t2];
        ulonglong2 kb = kp[base + t2 + 1];
        c0 += (ka.x > my);  c1 += (ka.y > my);
        c2 += (kb.x > my);  c3 += (kb.y > my);
        d0 += (ka.x > thr); d1 += (ka.y > thr);
        d2 += (kb.x > thr); d3 += (kb.y > thr);
    }
    partial[tid]  = (c0 + c1) + (c2 + c3);
    partial2[tid] = (d0 + d1) + (d2 + d3);
    __syncthreads();
    if (tid < 64) {
        int rank = 0, kc = 0;
        #pragma unroll
        for (int w = 0; w < 16; w++) {
            rank += partial[tid + 64*w];
            kc   += partial2[tid + 64*w];
        }
        unsigned long long km = keys[m0 + tid];
        unsigned int k32 = (unsigned int)(km >> 12);
        unsigned int u = (k32 & 0x80000000u) ? (k32 & 0x7fffffffu) : ~k32;
        ws[OFF_SC + b*N + rank] = __uint_as_float(u);
        ((int*)(ws + OFF_SIDX))[b*N + rank] = m0 + tid;
        ((int*)(ws + OFF_KN))[b*N + m0 + tid] = kc;
    }
}

// ------------------------------------------------------------------
// K3: 1024 thr, two-level scan. Wave w (0..15): 4-step local prefix of
// [g[m,i] ; c_m*g[m,i]] (64 channels); 16 segment offsets recombine.
__global__ __launch_bounds__(1024) void k_prefix(float* __restrict__ ws)
{
    __shared__ int   sidx[64];
    __shared__ float scv[64];
    __shared__ float pl_lds[64*64];      // [k][ch] (16 KB)
    __shared__ float wtot[16*64];
    __shared__ float segoff[16*64];
    const int tid = threadIdx.x;
    const int blk = blockIdx.x;          // b*NT + t
    const int b = blk / NT, t = blk % NT;
    const int k0 = t * 64;
    if (tid < 64) {
        sidx[tid] = ((const int*)(ws + OFF_SIDX))[b*N + k0 + tid];
        scv[tid]  = ws[OFF_SC + b*N + k0 + tid];
    }
    __syncthreads();
    const int w   = tid >> 6;            // k-segment (0..15)
    const int ch  = tid & 63;
    const int chm = ch & 31;
    const bool isCG = ch >= 32;
    const float* gx = ws + OFF_GX + (size_t)b*N*CI;
    float acc = 0.f;
    #pragma unroll
    for (int kk = 0; kk < 4; kk++) {
        int k = w*4 + kk;
        int m = sidx[k];                               // wave-uniform
        float gval = gx[(size_t)m*CI + chm];           // 128B gather, 2-way bcast
        float v = isCG ? gval * scv[k] : gval;
        pl_lds[k*64 + ch] = acc;
        acc += v;
    }
    wtot[w*64 + ch] = acc;
    __syncthreads();
    if (tid < 64) {
        float s = 0.f;
        #pragma unroll
        for (int ww = 0; ww < 16; ww++) { segoff[ww*64 + tid] = s; s += wtot[ww*64 + tid]; }
        ws[OFF_TOT + ((size_t)b*NT + t)*64 + tid] = s;     // tile total
    }
    __syncthreads();
    float* pl = ws + OFF_PLOC + ((size_t)b*N + k0)*64;
    #pragma unroll
    for (int r16 = 0; r16 < 4; r16++) {
        int r = w + r16*16;                                // covers 0..63
        pl[(size_t)r*64 + ch] = pl_lds[r*64 + ch] + segoff[(r >> 2)*64 + ch];
    }
}

// ------------------------------------------------------------------
// K4: 1024 thr. Per (b,tile): y via KN lookup + prefix; wy = W·y + W_b
// stored to OFF_WY; per-block BN partials (f32, no atomics).
__global__ __launch_bounds__(1024) void k_stats(
    const float* __restrict__ W_w, const float* __restrict__ W_b,
    float* __restrict__ ws)
{
    __shared__ float offs_lds[(NT+1)*64];    // 9472 B
    __shared__ float y_lds[64*33];           // 8448 B
    __shared__ float Wl[C*CI];               // 8192 B
    __shared__ float Wbl[C];
    const int tid = threadIdx.x;
    const int blk = blockIdx.x;
    const int b = blk / NT, tile = blk % NT;

    for (int i = tid; i < C*CI; i += 1024) Wl[i] = W_w[i];
    if (tid < C) Wbl[tid] = W_b[tid];
    {   // stage tile totals (coalesced)
        const float* tot = ws + OFF_TOT + (size_t)b*NT*64;
        for (int i = tid; i < NT*64; i += 1024) offs_lds[i] = tot[i];
    }
    __syncthreads();
    if (tid < 64) {   // in-LDS exclusive scan over tiles (per channel)
        float acc = 0.f;
        #pragma unroll 4
        for (int t = 0; t < NT; t++) {
            float v = offs_lds[t*64 + tid];
            offs_lds[t*64 + tid] = acc;
            acc += v;
        }
        offs_lds[NT*64 + tid] = acc;
    }
    __syncthreads();

    const int p = tid & 63, wv = tid >> 6;     // wv 0..15
    const int n = tile*64 + p;
    const float an = ws[OFF_A + b*N + n];
    const int k = ((const int*)(ws + OFF_KN))[b*N + n];
    const int kt = k >> 6;
    const float* pl = ws + OFF_PLOC + ((size_t)b*N + k)*64;
    const float inv_n = 1.0f / (float)N;
    #pragma unroll
    for (int q = 0; q < 2; q++) {              // 16 waves x 2 = CI values
        int i = wv*2 + q;
        float plg = (k < N) ? pl[i]      : 0.f;
        float plc = (k < N) ? pl[i + 32] : 0.f;
        float Pg = offs_lds[kt*64 + i]      + plg;
        float Pc = offs_lds[kt*64 + i + 32] + plc;
        y_lds[p*33 + i] = inv_n * (an * Pg + Pc);
    }
    __syncthreads();

    // hoist y[p][0..31] to registers (stride-33 -> conflict-free)
    float yv[CI];
    #pragma unroll
    for (int i = 0; i < CI; i++) yv[i] = y_lds[p*33 + i];

    const int lane = tid & 63;
    float* part = ws + OFF_PART + (size_t)blk*128;
    float* wyb  = ws + OFF_WY + (size_t)b*C*N + n;
    #pragma unroll
    for (int q = 0; q < 4; q++) {              // 16 waves x 4 = C channels
        int c = wv*4 + q;                      // wave-uniform
        float wyv = Wbl[c];
        #pragma unroll
        for (int i4 = 0; i4 < CI; i4 += 4) {
            float4 w4 = *(const float4*)(Wl + c*CI + i4);   // b128 broadcast
            wyv += w4.x*yv[i4] + w4.y*yv[i4+1] + w4.z*yv[i4+2] + w4.w*yv[i4+3];
        }
        wyb[(size_t)c*N] = wyv;                // coalesced over lanes
        float s = wyv, sq = wyv * wyv;
        #pragma unroll
        for (int off = 32; off >= 1; off >>= 1) {
            s  += __shfl_xor(s,  off, 64);
            sq += __shfl_xor(sq, off, 64);
        }
        if (lane == 0) { part[c] = s; part[64 + c] = sq; }
    }
}

// ------------------------------------------------------------------
// K5: 1024 thr. Per-block redundant reduce (8 eighths of 36 tiles) ->
// scale/shift, then stream out = wy*scale + shift + x (1 float4/thread).
__global__ __launch_bounds__(1024) void k_final(
    const float* __restrict__ x,
    const float* __restrict__ bn_g, const float* __restrict__ bn_b,
    const float* __restrict__ ws, float* __restrict__ out)
{
    __shared__ double red[1024];
    __shared__ float ssc[128];               // scale[64], shift[64]
    const int tid = threadIdx.x;
    {   // redundant per-block reduce (L2-resident, coalesced)
        const float* part = ws + OFF_PART;
        const int ch = tid & 127, e8 = tid >> 7;           // 8 eighths
        double acc = 0.0;
        #pragma unroll 4
        for (int k2 = 0; k2 < NTILES/8; k2++)
            acc += (double)part[(size_t)(e8*(NTILES/8) + k2)*128 + ch];
        red[tid] = acc;
    }
    __syncthreads();
    if (tid < 64) {
        double ssum = 0.0, ssq = 0.0;
        #pragma unroll
        for (int e = 0; e < 8; e++) {
            ssum += red[tid + 128*e];
            ssq  += red[tid + 64 + 128*e];
        }
        double mean = ssum / (double)NTOT;
        double var  = ssq / (double)NTOT - mean*mean;
        float rs  = (float)(1.0 / sqrt(var + BN_EPS));
        float scl = bn_g[tid] * rs;
        ssc[tid]      = scl;
        ssc[64 + tid] = bn_b[tid] - (float)mean * scl;
    }
    __syncthreads();
    const float4* wy4 = (const float4*)(ws + OFF_WY);
    const float4* x4p = (const float4*)x;
    float4*       o4p = (float4*)out;
    const int idx = blockIdx.x*1024 + tid;                 // float4 index (exact cover)
    const float4 w4 = wy4[idx];
    const float4 xv = x4p[idx];
    const int c = ((idx*4) / N) & 63;                      // row-uniform (N%4==0)
    const float s = ssc[c], sh = ssc[64 + c];
    float4 o;
    o.x = w4.x*s + sh + xv.x;
    o.y = w4.y*s + sh + xv.y;
    o.z = w4.z*s + sh + xv.z;
    o.w = w4.w*s + sh + xv.w;
    o4p[idx] = o;
}

// ------------------------------------------------------------------
extern "C" void kernel_launch(void* const* d_in, const int* in_sizes, int n_in,
                              void* d_out, int out_size, void* d_ws, size_t ws_size,
                              hipStream_t stream)
{
    const float* x     = (const float*)d_in[0];
    const float* g_w   = (const float*)d_in[1];
    const float* g_b   = (const float*)d_in[2];
    const float* th_w  = (const float*)d_in[3];
    const float* th_b  = (const float*)d_in[4];
    const float* ph_w  = (const float*)d_in[5];
    const float* ph_b  = (const float*)d_in[6];
    const float* cp_wt = (const float*)d_in[7];
    const float* cp_wp = (const float*)d_in[8];
    const float* W_w   = (const float*)d_in[9];
    const float* W_b   = (const float*)d_in[10];
    const float* bn_g  = (const float*)d_in[11];
    const float* bn_b  = (const float*)d_in[12];
    float* ws  = (float*)d_ws;
    float* out = (float*)d_out;

    hipLaunchKernelGGL(k_proj,   dim3(NTILES), dim3(1024), 0, stream,
                       x, g_w, g_b, th_w, th_b, ph_w, ph_b, cp_wt, cp_wp, ws);
    hipLaunchKernelGGL(k_rank,   dim3(NTILES), dim3(1024), 0, stream, ws);
    hipLaunchKernelGGL(k_prefix, dim3(NTILES), dim3(1024), 0, stream, ws);
    hipLaunchKernelGGL(k_stats,  dim3(NTILES), dim3(1024), 0, stream, W_w, W_b, ws);
    hipLaunchKernelGGL(k_final,  dim3(NTILES), dim3(1024), 0, stream,
                       x, bn_g, bn_b, ws, out);
}